// Round 4
// baseline (4854.609 us; speedup 1.0000x reference)
//
#include <hip/hip_runtime.h>
#include <cstdint>
#include <cstddef>

// may_alias punning types (used only for float4 vector moves)
typedef float4 __attribute__((may_alias)) float4_a;

constexpr int SEQ    = 4096;
constexpr int HID    = 2048;
constexpr int NHEADS = 16;
constexpr int NKVH   = 4;
constexpr int HDIM   = 128;
constexpr int QD     = NHEADS * HDIM;  // 2048
constexpr int KVD    = NKVH * HDIM;    // 512

// ---------------------------------------------------------------------------
// GEMM: C[M,N] = A[M,K] (row stride lda) * B[K,N] (row stride ldb), all fp32.
// accum!=0 -> C += result. Block 256; BM=128 BN=64 BK=16; 8x4 register tile.
// M%128==0, N%64==0, K%16==0, lda/ldb multiples of 4.
// ---------------------------------------------------------------------------
constexpr int BM = 128, BN = 64, BK = 16;

__global__ __launch_bounds__(256) void gemm_f32_kernel(
    const float* __restrict__ A, int lda, const float* __restrict__ B, int ldb,
    float* __restrict__ C, int M, int N, int K, int accum)
{
    __shared__ float s_a[BK][BM + 4];   // rows 528 B (16B-aligned)
    __shared__ float s_b[BK][BN];

    const int tid = threadIdx.x;
    const int tn  = tid & 15;           // cols tn*4..+3
    const int tm  = tid >> 4;           // rows tm*8..+7
    const int m_base = blockIdx.y * BM;
    const int n_base = blockIdx.x * BN;

    const int a_row = tid >> 1;         // 0..127
    const int a_k   = (tid & 1) * 8;    // 0 or 8
    const int b_k   = tid >> 4;         // 0..15
    const int b_n   = (tid & 15) * 4;   // 0..60

    const float* Ag = A + (size_t)(m_base + a_row) * lda + a_k;
    const float* Bg = B + (size_t)b_k * ldb + (n_base + b_n);

    float acc[8][4];
#pragma unroll
    for (int i = 0; i < 8; i++)
#pragma unroll
        for (int j = 0; j < 4; j++) acc[i][j] = 0.f;

    for (int kb = 0; kb < K; kb += BK) {
        // A tile: 8 contiguous fp32 along K per thread, stored transposed
        float4 a0 = *(const float4_a*)(Ag + kb);
        float4 a1 = *(const float4_a*)(Ag + kb + 4);
        s_a[a_k + 0][a_row] = a0.x;
        s_a[a_k + 1][a_row] = a0.y;
        s_a[a_k + 2][a_row] = a0.z;
        s_a[a_k + 3][a_row] = a0.w;
        s_a[a_k + 4][a_row] = a1.x;
        s_a[a_k + 5][a_row] = a1.y;
        s_a[a_k + 6][a_row] = a1.z;
        s_a[a_k + 7][a_row] = a1.w;
        // B tile: 4 contiguous fp32 along N per thread
        *(float4_a*)&s_b[b_k][b_n] = *(const float4_a*)(Bg + (size_t)kb * ldb);

        __syncthreads();
#pragma unroll
        for (int k = 0; k < BK; k++) {
            float4 b4  = *(const float4_a*)&s_b[k][tn * 4];
            float4 av0 = *(const float4_a*)&s_a[k][tm * 8];
            float4 av1 = *(const float4_a*)&s_a[k][tm * 8 + 4];
            float ar[8] = {av0.x, av0.y, av0.z, av0.w, av1.x, av1.y, av1.z, av1.w};
            float br[4] = {b4.x, b4.y, b4.z, b4.w};
#pragma unroll
            for (int i = 0; i < 8; i++)
#pragma unroll
                for (int j = 0; j < 4; j++)
                    acc[i][j] = fmaf(ar[i], br[j], acc[i][j]);
        }
        __syncthreads();
    }

#pragma unroll
    for (int i = 0; i < 8; i++) {
        float* cp = C + (size_t)(m_base + tm * 8 + i) * N + n_base + tn * 4;
        float4 o = make_float4(acc[i][0], acc[i][1], acc[i][2], acc[i][3]);
        if (accum) {
            float4 old = *(const float4_a*)cp;
            o.x += old.x; o.y += old.y; o.z += old.z; o.w += old.w;
        }
        *(float4_a*)cp = o;
    }
}

// ---------------------------------------------------------------------------
// RoPE in-place on a [SEQ, nh*128] fp32 buffer. One thread per (s, head, i<64).
// Precise sincosf: angles reach 4095 rad (652 revolutions), beyond HW v_sin range.
// ---------------------------------------------------------------------------
__global__ __launch_bounds__(256) void rope_kernel(
    float* __restrict__ buf, int nh, const int* __restrict__ pos_ids)
{
    int idx  = blockIdx.x * blockDim.x + threadIdx.x;   // SEQ*nh*64 total
    int i    = idx & 63;
    int rem  = idx >> 6;
    int head = rem % nh;
    int s    = rem / nh;
    if (s >= SEQ) return;

    float pos = (float)pos_ids[s];
    float ang = pos * __expf(-(float)i * 0.14391156831212787f);  // ln(1e4)/64
    float c, sn;
    sincosf(ang, &sn, &c);

    float* p = buf + (size_t)s * (nh * HDIM) + head * HDIM;
    float x0 = p[i];
    float x1 = p[i + 64];
    p[i]      = x0 * c - x1 * sn;
    p[i + 64] = x1 * c + x0 * sn;
}

// ---------------------------------------------------------------------------
// Flash attention, causal, GQA (n_rep=4). All fp32. Q/O row stride = nhbuf*128;
// head_base maps local head -> global head for KV selection.
// Q and O intentionally alias in-place: block (q0,hloc) stages its Q tile to
// LDS first and only ever overwrites that exact region. No __restrict__ on them.
// ---------------------------------------------------------------------------
constexpr int QT = 32, KT = 32;
constexpr int HDP = HDIM + 4;   // 132 floats/row: 16B-aligned rows, conflict-broken

static __device__ __forceinline__ void load16_f32(const float* src, float* dst) {
#pragma unroll
    for (int q = 0; q < 4; q++)
        ((float4_a*)dst)[q] = ((const float4_a*)src)[q];
}

__global__ __launch_bounds__(256) void flash_kernel(
    const float* Q, int nhbuf, int head_base,
    const float* __restrict__ Kb, const float* __restrict__ Vb,
    const int* __restrict__ amask, float* O)
{
    __shared__ float qs[QT][HDP];
    __shared__ float ks[KT][HDP];
    __shared__ float vs[KT][HDP];
    __shared__ float sc[QT][KT + 1];
    __shared__ float mrow[QT], lrow[QT], arow[QT];
    __shared__ int   kmask[KT];

    const int tid  = threadIdx.x;
    const int hloc = blockIdx.y;
    const int kvh  = (head_base + hloc) >> 2;     // n_rep = 4
    const int qd   = nhbuf * HDIM;                // Q/O row stride
    const int q0   = (gridDim.x - 1 - blockIdx.x) * QT;  // longest blocks first

    const int r  = tid >> 3;        // 0..31
    const int c8 = tid & 7;         // 0..7
    const int dl = c8 * 16;

    load16_f32(Q + (size_t)(q0 + r) * qd + hloc * HDIM + dl, &qs[r][dl]);
    if (tid < QT) { mrow[tid] = -1e30f; lrow[tid] = 0.f; }

    float acc[16];
#pragma unroll
    for (int i = 0; i < 16; i++) acc[i] = 0.f;
    const float scale = 0.08838834764831845f;     // 1/sqrt(128)

    const int ktiles = (q0 >> 5) + 1;
    for (int kt = 0; kt < ktiles; kt++) {
        const int k0 = kt * KT;
        __syncthreads();   // covers Q staging/init on iter 0; protects ks/vs reuse
        load16_f32(Kb + (size_t)(k0 + r) * KVD + kvh * HDIM + dl, &ks[r][dl]);
        load16_f32(Vb + (size_t)(k0 + r) * KVD + kvh * HDIM + dl, &vs[r][dl]);
        if (tid < KT) kmask[tid] = amask[k0 + tid];
        __syncthreads();

        {   // S = Q K^T: row r, cols c8 + {0,8,16,24}
            float s0 = 0.f, s1 = 0.f, s2 = 0.f, s3 = 0.f;
#pragma unroll 8
            for (int cc = 0; cc < 32; cc++) {
                float4 qv  = *(const float4_a*)&qs[r][cc * 4];
                float4 k0v = *(const float4_a*)&ks[c8][cc * 4];
                float4 k1v = *(const float4_a*)&ks[c8 + 8][cc * 4];
                float4 k2v = *(const float4_a*)&ks[c8 + 16][cc * 4];
                float4 k3v = *(const float4_a*)&ks[c8 + 24][cc * 4];
                s0 = fmaf(qv.x, k0v.x, s0); s0 = fmaf(qv.y, k0v.y, s0);
                s0 = fmaf(qv.z, k0v.z, s0); s0 = fmaf(qv.w, k0v.w, s0);
                s1 = fmaf(qv.x, k1v.x, s1); s1 = fmaf(qv.y, k1v.y, s1);
                s1 = fmaf(qv.z, k1v.z, s1); s1 = fmaf(qv.w, k1v.w, s1);
                s2 = fmaf(qv.x, k2v.x, s2); s2 = fmaf(qv.y, k2v.y, s2);
                s2 = fmaf(qv.z, k2v.z, s2); s2 = fmaf(qv.w, k2v.w, s2);
                s3 = fmaf(qv.x, k3v.x, s3); s3 = fmaf(qv.y, k3v.y, s3);
                s3 = fmaf(qv.z, k3v.z, s3); s3 = fmaf(qv.w, k3v.w, s3);
            }
            float vals[4] = {s0, s1, s2, s3};
#pragma unroll
            for (int ci = 0; ci < 4; ci++) {
                int j = c8 + 8 * ci;
                float val = vals[ci] * scale;
                if ((k0 + j > q0 + r) || (kmask[j] == 0)) val = -1e30f;
                sc[r][j] = val;
            }
        }
        __syncthreads();

        if (tid < QT) {   // online softmax, one thread per q-row
            float m_old = mrow[tid];
            float mt = m_old;
#pragma unroll 8
            for (int j = 0; j < KT; j++) mt = fmaxf(mt, sc[tid][j]);
            float al = __expf(m_old - mt);
            float sum = 0.f;
#pragma unroll 8
            for (int j = 0; j < KT; j++) {
                float p = __expf(sc[tid][j] - mt);
                sc[tid][j] = p;
                sum += p;
            }
            lrow[tid] = lrow[tid] * al + sum;
            mrow[tid] = mt;
            arow[tid] = al;
        }
        __syncthreads();

        {   // O += P V: row r, dims c8*4 + 32*qq + {0..3}
            float al = arow[r];
#pragma unroll
            for (int i = 0; i < 16; i++) acc[i] *= al;
#pragma unroll 4
            for (int j = 0; j < KT; j++) {
                float p = sc[r][j];
#pragma unroll
                for (int qq = 0; qq < 4; qq++) {
                    float4 vv = *(const float4_a*)&vs[j][c8 * 4 + 32 * qq];
                    acc[qq * 4 + 0] = fmaf(p, vv.x, acc[qq * 4 + 0]);
                    acc[qq * 4 + 1] = fmaf(p, vv.y, acc[qq * 4 + 1]);
                    acc[qq * 4 + 2] = fmaf(p, vv.z, acc[qq * 4 + 2]);
                    acc[qq * 4 + 3] = fmaf(p, vv.w, acc[qq * 4 + 3]);
                }
            }
        }
    }

    float linv = 1.0f / lrow[r];
    float* op = O + (size_t)(q0 + r) * qd + hloc * HDIM;
#pragma unroll
    for (int qq = 0; qq < 4; qq++) {
        float4 o = make_float4(acc[qq * 4 + 0] * linv, acc[qq * 4 + 1] * linv,
                               acc[qq * 4 + 2] * linv, acc[qq * 4 + 3] * linv);
        *(float4_a*)(op + c8 * 4 + 32 * qq) = o;
    }
}

// ---------------------------------------------------------------------------
// THEORY R3: R1-R3 NaN was a dtype bug — the reference is pure float32, we
// read the buffers as bf16 (low-half fp32 mantissas as bf16 -> ~0.4% NaN).
// Everything is now fp32 per the harness contract. ws-adaptive tiers kept
// (fp32 sizes: tier1=48MB, tier2=32MB + k/v in d_out, tier3=grouped heads).
// ---------------------------------------------------------------------------
extern "C" void kernel_launch(void* const* d_in, const int* in_sizes, int n_in,
                              void* d_out, int out_size, void* d_ws, size_t ws_size,
                              hipStream_t stream)
{
    const float* x     = (const float*)d_in[0];   // [4096, 2048]
    const int*   amask = (const int*)d_in[1];     // [4096]
    const int*   pos   = (const int*)d_in[2];     // [4096]
    const float* wq    = (const float*)d_in[3];   // [2048, 2048]
    const float* wk    = (const float*)d_in[4];   // [2048, 512]
    const float* wv    = (const float*)d_in[5];   // [2048, 512]
    const float* wo    = (const float*)d_in[6];   // [2048, 2048]
    float* out = (float*)d_out;                   // [4096, 2048]
    float* ws  = (float*)d_ws;

    const size_t MB = 1ull << 20;
    dim3 blk(256);

    if (ws_size >= 48 * MB) {
        // Tier 1: q/att (32 MB, in-place flash) + k (8 MB) + v (8 MB) in ws.
        float* qbuf = ws;
        float* kbuf = ws + (size_t)SEQ * QD;
        float* vbuf = kbuf + (size_t)SEQ * KVD;
        gemm_f32_kernel<<<dim3(QD / BN, SEQ / BM), blk, 0, stream>>>(x, HID, wq, QD, qbuf, SEQ, QD, HID, 0);
        gemm_f32_kernel<<<dim3(KVD / BN, SEQ / BM), blk, 0, stream>>>(x, HID, wk, KVD, kbuf, SEQ, KVD, HID, 0);
        gemm_f32_kernel<<<dim3(KVD / BN, SEQ / BM), blk, 0, stream>>>(x, HID, wv, KVD, vbuf, SEQ, KVD, HID, 0);
        rope_kernel<<<SEQ * NHEADS / 4, blk, 0, stream>>>(qbuf, NHEADS, pos);
        rope_kernel<<<SEQ * NKVH / 4, blk, 0, stream>>>(kbuf, NKVH, pos);
        flash_kernel<<<dim3(SEQ / QT, NHEADS), blk, 0, stream>>>(qbuf, NHEADS, 0, kbuf, vbuf, amask, qbuf);
        gemm_f32_kernel<<<dim3(HID / BN, SEQ / BM), blk, 0, stream>>>(qbuf, QD, wo, HID, out, SEQ, HID, QD, 0);
    } else if (ws_size >= 32 * MB) {
        // Tier 2: q/att in ws (32 MB); k/v scratch inside d_out (16 of 32 MB),
        // fully consumed by flash before the final GEMM overwrites d_out.
        float* qbuf = ws;
        float* kbuf = out;
        float* vbuf = out + (size_t)SEQ * KVD;
        gemm_f32_kernel<<<dim3(QD / BN, SEQ / BM), blk, 0, stream>>>(x, HID, wq, QD, qbuf, SEQ, QD, HID, 0);
        gemm_f32_kernel<<<dim3(KVD / BN, SEQ / BM), blk, 0, stream>>>(x, HID, wk, KVD, kbuf, SEQ, KVD, HID, 0);
        gemm_f32_kernel<<<dim3(KVD / BN, SEQ / BM), blk, 0, stream>>>(x, HID, wv, KVD, vbuf, SEQ, KVD, HID, 0);
        rope_kernel<<<SEQ * NHEADS / 4, blk, 0, stream>>>(qbuf, NHEADS, pos);
        rope_kernel<<<SEQ * NKVH / 4, blk, 0, stream>>>(kbuf, NKVH, pos);
        flash_kernel<<<dim3(SEQ / QT, NHEADS), blk, 0, stream>>>(qbuf, NHEADS, 0, kbuf, vbuf, amask, qbuf);
        gemm_f32_kernel<<<dim3(HID / BN, SEQ / BM), blk, 0, stream>>>(qbuf, QD, wo, HID, out, SEQ, HID, QD, 0);
    } else {
        // Tier 3: k/v in ws (16 MB) + G-head q/att group buffer (G*2 MB).
        int avail = (int)(ws_size / MB) - 16; if (avail < 2) avail = 2;
        int G = 1; while (G * 4 <= avail && G * 2 <= NHEADS) G *= 2;
        float* kbuf = ws;
        float* vbuf = ws + (size_t)SEQ * KVD;
        float* qg   = vbuf + (size_t)SEQ * KVD;
        const int GN = G * HDIM;
        gemm_f32_kernel<<<dim3(KVD / BN, SEQ / BM), blk, 0, stream>>>(x, HID, wk, KVD, kbuf, SEQ, KVD, HID, 0);
        gemm_f32_kernel<<<dim3(KVD / BN, SEQ / BM), blk, 0, stream>>>(x, HID, wv, KVD, vbuf, SEQ, KVD, HID, 0);
        rope_kernel<<<SEQ * NKVH / 4, blk, 0, stream>>>(kbuf, NKVH, pos);
        for (int g = 0; g < NHEADS / G; g++) {
            gemm_f32_kernel<<<dim3(GN / BN, SEQ / BM), blk, 0, stream>>>(
                x, HID, wq + (size_t)g * GN, QD, qg, SEQ, GN, HID, 0);
            rope_kernel<<<SEQ * G / 4, blk, 0, stream>>>(qg, G, pos);
            flash_kernel<<<dim3(SEQ / QT, G), blk, 0, stream>>>(qg, G, g * G, kbuf, vbuf, amask, qg);
            gemm_f32_kernel<<<dim3(HID / BN, SEQ / BM), blk, 0, stream>>>(
                qg, GN, wo + (size_t)g * GN * HID, HID, out, SEQ, HID, GN, g > 0 ? 1 : 0);
        }
    }
}

// Round 5
// 942.081 us; speedup vs baseline: 5.1531x; 5.1531x over previous
//
#include <hip/hip_runtime.h>
#include <cstdint>
#include <cstddef>

typedef unsigned short ushort_t;
typedef short    bf16x8 __attribute__((ext_vector_type(8)));   // MFMA A/B frag (4 VGPR)
typedef float    f32x4  __attribute__((ext_vector_type(4)));   // MFMA C/D frag
typedef uint4    __attribute__((may_alias)) uint4_a;
typedef ushort4  __attribute__((may_alias)) ushort4_a;
typedef float4   __attribute__((may_alias)) float4_a;

constexpr int SEQ = 4096, HID = 2048, NHEADS = 16, NKVH = 4, HDIM = 128;
constexpr int QD  = NHEADS * HDIM;   // 2048
constexpr int KVD = NKVH * HDIM;     // 512

static __device__ __forceinline__ float bf2f(ushort_t u) {
    return __uint_as_float(((unsigned)u) << 16);
}
static __device__ __forceinline__ ushort_t f2bf(float f) {
    unsigned x = __float_as_uint(f);
    unsigned r = x + 0x7FFFu + ((x >> 16) & 1u);   // RNE
    return (ushort_t)(r >> 16);
}
static __device__ __forceinline__ unsigned pack2(float lo, float hi) {
    return (unsigned)f2bf(lo) | ((unsigned)f2bf(hi) << 16);
}
static __device__ __forceinline__ bf16x8 u4_to_frag(uint4 u) {
    union { uint4 u; bf16x8 v; } cv; cv.u = u; return cv.v;
}

// ---------------------------------------------------------------------------
// X fp32 -> bf16 elementwise (one-shot scratch prep)
// ---------------------------------------------------------------------------
__global__ __launch_bounds__(256) void cast_f32_bf16(
    const float* __restrict__ in, ushort_t* __restrict__ out, int n)
{
    int i = (blockIdx.x * 256 + threadIdx.x) * 8;
    if (i >= n) return;
    float4 a = *(const float4_a*)(in + i);
    float4 b = *(const float4_a*)(in + i + 4);
    uint4 o;
    o.x = pack2(a.x, a.y); o.y = pack2(a.z, a.w);
    o.z = pack2(b.x, b.y); o.w = pack2(b.z, b.w);
    *(uint4_a*)(out + i) = o;
}

// ---------------------------------------------------------------------------
// W[K,N] fp32 -> WT[N,K] bf16 (32x32 LDS-tiled transpose+cast)
// grid = (K/32, N/32)
// ---------------------------------------------------------------------------
__global__ __launch_bounds__(256) void transpose_cast(
    const float* __restrict__ W, ushort_t* __restrict__ WT, int K, int N)
{
    __shared__ float tl[32][36];   // pad 36: 144B rows, 16B-aligned
    const int k0 = blockIdx.x * 32, n0 = blockIdx.y * 32;
    const int t  = threadIdx.x;
    {
        int i = t >> 3, jb = (t & 7) * 4;
        *(float4_a*)&tl[i][jb] = *(const float4_a*)(W + (size_t)(k0 + i) * N + n0 + jb);
    }
    __syncthreads();
    {
        int n = t >> 3, kb = (t & 7) * 4;
        ushort4 o;
        o.x = f2bf(tl[kb + 0][n]); o.y = f2bf(tl[kb + 1][n]);
        o.z = f2bf(tl[kb + 2][n]); o.w = f2bf(tl[kb + 3][n]);
        *(ushort4_a*)(WT + (size_t)(n0 + n) * K + k0 + kb) = o;
    }
}

// ---------------------------------------------------------------------------
// MFMA GEMM: C[M,N] = A[M,K] * Bt[N,K]^T, A/Bt bf16, fp32 acc.
// Block 256 (4 waves), tile 128x128, BK=32. Wave: 64x64 = 4x4 MFMA tiles.
// Frag layouts (guide, HW-verified): A/B lane&15 = m/n, k = (lane>>4)*8+j;
// C/D col = lane&15, row = (lane>>4)*4 + reg.
// out_f32: 1 -> C fp32, else bf16.
// ---------------------------------------------------------------------------
__global__ __launch_bounds__(256) void gemm_mfma(
    const ushort_t* __restrict__ A, int lda,
    const ushort_t* __restrict__ Bt, int ldb,
    void* __restrict__ C, int M, int N, int K, int out_f32)
{
    __shared__ ushort_t as[128][40];   // pad 40: 80B rows (16B-aligned, 2-way banks)
    __shared__ ushort_t bs[128][40];

    const int t    = threadIdx.x;
    const int mb   = blockIdx.y * 128, nb = blockIdx.x * 128;
    const int w    = t >> 6, lane = t & 63, quad = lane >> 4, l15 = lane & 15;
    const int wm   = (w >> 1) * 64, wn = (w & 1) * 64;
    const int srow = t >> 1, koff = (t & 1) * 16;

    f32x4 acc[4][4];
#pragma unroll
    for (int i = 0; i < 4; i++)
#pragma unroll
        for (int j = 0; j < 4; j++) acc[i][j] = (f32x4)0.f;

    const ushort_t* Ag = A  + (size_t)(mb + srow) * lda + koff;
    const ushort_t* Bg = Bt + (size_t)(nb + srow) * ldb + koff;

    for (int kb = 0; kb < K; kb += 32) {
        uint4 av0 = *(const uint4_a*)(Ag + kb);
        uint4 av1 = *(const uint4_a*)(Ag + kb + 8);
        uint4 bv0 = *(const uint4_a*)(Bg + kb);
        uint4 bv1 = *(const uint4_a*)(Bg + kb + 8);
        __syncthreads();   // previous iter's frag reads done
        *(uint4_a*)&as[srow][koff]     = av0;
        *(uint4_a*)&as[srow][koff + 8] = av1;
        *(uint4_a*)&bs[srow][koff]     = bv0;
        *(uint4_a*)&bs[srow][koff + 8] = bv1;
        __syncthreads();

        bf16x8 af[4], bf[4];
#pragma unroll
        for (int mt = 0; mt < 4; mt++)
            af[mt] = *(const bf16x8*)&as[wm + mt * 16 + l15][quad * 8];
#pragma unroll
        for (int nt = 0; nt < 4; nt++)
            bf[nt] = *(const bf16x8*)&bs[wn + nt * 16 + l15][quad * 8];
#pragma unroll
        for (int mt = 0; mt < 4; mt++)
#pragma unroll
            for (int nt = 0; nt < 4; nt++)
                acc[mt][nt] = __builtin_amdgcn_mfma_f32_16x16x32_bf16(
                    af[mt], bf[nt], acc[mt][nt], 0, 0, 0);
    }

#pragma unroll
    for (int mt = 0; mt < 4; mt++)
#pragma unroll
        for (int nt = 0; nt < 4; nt++)
#pragma unroll
            for (int r = 0; r < 4; r++) {
                int row = mb + wm + mt * 16 + quad * 4 + r;
                int col = nb + wn + nt * 16 + l15;
                float v = acc[mt][nt][r];
                if (out_f32) ((float*)C)[(size_t)row * N + col] = v;
                else         ((ushort_t*)C)[(size_t)row * N + col] = f2bf(v);
            }
}

// ---------------------------------------------------------------------------
// RoPE in-place on bf16 [SEQ, nh*128]; precise sincosf (650+ revolutions).
// ---------------------------------------------------------------------------
__global__ __launch_bounds__(256) void rope_bf16(
    ushort_t* __restrict__ buf, int nh, const int* __restrict__ pos_ids)
{
    int idx  = blockIdx.x * 256 + threadIdx.x;
    int i    = idx & 63;
    int rem  = idx >> 6;
    int head = rem % nh;
    int s    = rem / nh;
    if (s >= SEQ) return;

    float pos = (float)pos_ids[s];
    float ang = pos * __expf(-(float)i * 0.14391156831212787f);  // ln(1e4)/64
    float c, sn;
    sincosf(ang, &sn, &c);

    ushort_t* p = buf + (size_t)s * (nh * HDIM) + head * HDIM;
    float x0 = bf2f(p[i]);
    float x1 = bf2f(p[i + 64]);
    p[i]      = f2bf(x0 * c - x1 * sn);
    p[i + 64] = f2bf(x1 * c + x0 * sn);
}

// ---------------------------------------------------------------------------
// MFMA flash attention, causal, GQA (n_rep=4), bf16 in/out, fp32 softmax/acc.
// Block 256 = 4 waves; block covers 64 q rows of one head; 32-key tiles.
// Q frags: register-resident from global. K frags: direct global (L1/L2).
// V: LDS transposed vt[dim][key]. P: wave-private LDS round-trip C->A layout.
// Q/O alias in-place (block reads its region into regs first, writes it last).
// ---------------------------------------------------------------------------
__global__ __launch_bounds__(256) void flash_mfma(
    const ushort_t* Q, const ushort_t* __restrict__ Kb,
    const ushort_t* __restrict__ Vb, const int* __restrict__ amask,
    ushort_t* O)
{
    __shared__ ushort_t vt[128][40];     // V^T tile: [dim][key], 80B rows
    __shared__ float    pm[4][16][36];   // per-wave P scratch [row][key], 144B rows
    __shared__ int      kmask[32];

    const int t    = threadIdx.x, w = t >> 6, lane = t & 63;
    const int quad = lane >> 4, l15 = lane & 15;
    const int h    = blockIdx.y, kvh = h >> 2;
    const int q0   = (gridDim.x - 1 - blockIdx.x) * 64;   // longest blocks first

    // Q fragments: rows q0 + w*16 + l15, k = c*32 + quad*8 + j
    bf16x8 qf[4];
    {
        const ushort_t* qp = Q + (size_t)(q0 + w * 16 + l15) * QD + h * HDIM;
#pragma unroll
        for (int c = 0; c < 4; c++)
            qf[c] = *(const bf16x8*)(qp + c * 32 + quad * 8);
    }

    f32x4 accO[8];
#pragma unroll
    for (int i = 0; i < 8; i++) accO[i] = (f32x4)0.f;
    float m_r[4], l_r[4];
#pragma unroll
    for (int r = 0; r < 4; r++) { m_r[r] = -1e30f; l_r[r] = 0.f; }
    const float scale = 0.08838834764831845f;   // 1/sqrt(128)

    const int nkt = (q0 >> 5) + 2;   // keys 0 .. q0+63
    for (int kt = 0; kt < nkt; kt++) {
        const int k0 = kt * 32;
        __syncthreads();   // protect vt/kmask reuse
        {   // stage V^T: thread: key = t&31, dims dgroup*16..+15
            int key = t & 31, dbase = (t >> 5) * 16;
            const ushort_t* vp = Vb + (size_t)(k0 + key) * KVD + kvh * HDIM + dbase;
            uint4 v0 = *(const uint4_a*)vp;
            uint4 v1 = *(const uint4_a*)(vp + 8);
            unsigned wd[8] = {v0.x, v0.y, v0.z, v0.w, v1.x, v1.y, v1.z, v1.w};
#pragma unroll
            for (int i = 0; i < 8; i++) {
                vt[dbase + 2 * i][key]     = (ushort_t)(wd[i] & 0xFFFFu);
                vt[dbase + 2 * i + 1][key] = (ushort_t)(wd[i] >> 16);
            }
            if (t < 32) kmask[t] = amask[k0 + t];
        }
        __syncthreads();

        // S = Q K^T (2 n-tiles of 16 keys), K frags direct from global
        f32x4 s[2];
#pragma unroll
        for (int nt = 0; nt < 2; nt++) {
            s[nt] = (f32x4)0.f;
            const ushort_t* kp = Kb + (size_t)(k0 + nt * 16 + l15) * KVD + kvh * HDIM;
#pragma unroll
            for (int c = 0; c < 4; c++) {
                bf16x8 kf = *(const bf16x8*)(kp + c * 32 + quad * 8);
                s[nt] = __builtin_amdgcn_mfma_f32_16x16x32_bf16(qf[c], kf, s[nt], 0, 0, 0);
            }
        }

        // mask + scale + online softmax (rows quad*4+r; 16 key-lanes per quad)
        int km0 = kmask[l15], km1 = kmask[16 + l15];
        float p0[4], p1[4], alpha[4];
#pragma unroll
        for (int r = 0; r < 4; r++) {
            int row = q0 + w * 16 + quad * 4 + r;
            float v0 = s[0][r] * scale;
            float v1 = s[1][r] * scale;
            if (k0 + l15 > row      || km0 == 0) v0 = -1e30f;
            if (k0 + 16 + l15 > row || km1 == 0) v1 = -1e30f;
            float tmax = fmaxf(v0, v1);
            tmax = fmaxf(tmax, __shfl_xor(tmax, 1));
            tmax = fmaxf(tmax, __shfl_xor(tmax, 2));
            tmax = fmaxf(tmax, __shfl_xor(tmax, 4));
            tmax = fmaxf(tmax, __shfl_xor(tmax, 8));
            float mnew = fmaxf(m_r[r], tmax);
            alpha[r] = __expf(m_r[r] - mnew);
            m_r[r] = mnew;
            p0[r] = __expf(v0 - mnew);
            p1[r] = __expf(v1 - mnew);
            float ts = p0[r] + p1[r];
            ts += __shfl_xor(ts, 1);
            ts += __shfl_xor(ts, 2);
            ts += __shfl_xor(ts, 4);
            ts += __shfl_xor(ts, 8);
            l_r[r] = l_r[r] * alpha[r] + ts;
        }
#pragma unroll
        for (int i = 0; i < 8; i++) {
            f32x4 a = accO[i];
            a[0] *= alpha[0]; a[1] *= alpha[1]; a[2] *= alpha[2]; a[3] *= alpha[3];
            accO[i] = a;
        }

        // P: C-layout -> A-layout via wave-private LDS (no barrier needed)
#pragma unroll
        for (int r = 0; r < 4; r++) {
            pm[w][quad * 4 + r][l15]      = p0[r];
            pm[w][quad * 4 + r][16 + l15] = p1[r];
        }
        float4 pa0 = *(const float4_a*)&pm[w][l15][quad * 8];
        float4 pa1 = *(const float4_a*)&pm[w][l15][quad * 8 + 4];
        uint4 pu;
        pu.x = pack2(pa0.x, pa0.y); pu.y = pack2(pa0.z, pa0.w);
        pu.z = pack2(pa1.x, pa1.y); pu.w = pack2(pa1.z, pa1.w);
        bf16x8 pf = u4_to_frag(pu);

        // O += P V
#pragma unroll
        for (int nt8 = 0; nt8 < 8; nt8++) {
            bf16x8 vf = *(const bf16x8*)&vt[nt8 * 16 + l15][quad * 8];
            accO[nt8] = __builtin_amdgcn_mfma_f32_16x16x32_bf16(pf, vf, accO[nt8], 0, 0, 0);
        }
    }

    // epilogue: normalize, store bf16 in-place over this block's Q region
#pragma unroll
    for (int r = 0; r < 4; r++) {
        float linv = 1.0f / l_r[r];
        int row = q0 + w * 16 + quad * 4 + r;
        ushort_t* op = O + (size_t)row * QD + h * HDIM;
#pragma unroll
        for (int nt8 = 0; nt8 < 8; nt8++)
            op[nt8 * 16 + l15] = f2bf(accO[nt8][r] * linv);
    }
}

// ---------------------------------------------------------------------------
// Memory plan (ws >= 32MB proven by R4; we use 24MB):
//   ws   : qbuf/att bf16 16MB (flash in-place) | kbuf 4MB | vbuf 4MB
//          woT (8MB) overwrites kbuf+vbuf AFTER flash consumed them.
//   d_out: scratch until final GEMM: wqT 8MB | wkT 2MB | wvT 2MB | xb 16MB (=28MB)
//          final GEMM reads only ws, writes all of d_out.
// ---------------------------------------------------------------------------
extern "C" void kernel_launch(void* const* d_in, const int* in_sizes, int n_in,
                              void* d_out, int out_size, void* d_ws, size_t ws_size,
                              hipStream_t stream)
{
    const float* x     = (const float*)d_in[0];
    const int*   amask = (const int*)d_in[1];
    const int*   pos   = (const int*)d_in[2];
    const float* wq    = (const float*)d_in[3];
    const float* wk    = (const float*)d_in[4];
    const float* wv    = (const float*)d_in[5];
    const float* wo    = (const float*)d_in[6];
    float* out = (float*)d_out;

    ushort_t* wqT = (ushort_t*)d_out;                      // [QD=2048][HID=2048]
    ushort_t* wkT = wqT + (size_t)QD * HID;                // [KVD=512][HID]
    ushort_t* wvT = wkT + (size_t)KVD * HID;               // [KVD][HID]
    ushort_t* xb  = wvT + (size_t)KVD * HID;               // [SEQ][HID]

    ushort_t* qbuf = (ushort_t*)d_ws;                      // [SEQ][QD]
    ushort_t* kbuf = qbuf + (size_t)SEQ * QD;              // [SEQ][KVD]
    ushort_t* vbuf = kbuf + (size_t)SEQ * KVD;             // [SEQ][KVD]
    ushort_t* woT  = kbuf;                                 // [HID][QD] after flash

    cast_f32_bf16<<<SEQ * HID / 8 / 256, 256, 0, stream>>>(x, xb, SEQ * HID);
    transpose_cast<<<dim3(HID / 32, QD / 32),  256, 0, stream>>>(wq, wqT, HID, QD);
    transpose_cast<<<dim3(HID / 32, KVD / 32), 256, 0, stream>>>(wk, wkT, HID, KVD);
    transpose_cast<<<dim3(HID / 32, KVD / 32), 256, 0, stream>>>(wv, wvT, HID, KVD);

    gemm_mfma<<<dim3(QD / 128,  SEQ / 128), 256, 0, stream>>>(xb, HID, wqT, HID, qbuf, SEQ, QD,  HID, 0);
    gemm_mfma<<<dim3(KVD / 128, SEQ / 128), 256, 0, stream>>>(xb, HID, wkT, HID, kbuf, SEQ, KVD, HID, 0);
    gemm_mfma<<<dim3(KVD / 128, SEQ / 128), 256, 0, stream>>>(xb, HID, wvT, HID, vbuf, SEQ, KVD, HID, 0);

    rope_bf16<<<SEQ * NHEADS * 64 / 256, 256, 0, stream>>>(qbuf, NHEADS, pos);
    rope_bf16<<<SEQ * NKVH  * 64 / 256, 256, 0, stream>>>(kbuf, NKVH, pos);

    flash_mfma<<<dim3(SEQ / 64, NHEADS), 256, 0, stream>>>(qbuf, kbuf, vbuf, amask, qbuf);

    transpose_cast<<<dim3(QD / 32, HID / 32), 256, 0, stream>>>(wo, woT, QD, HID);
    gemm_mfma<<<dim3(HID / 128, SEQ / 128), 256, 0, stream>>>(qbuf, QD, woT, QD, out, SEQ, HID, QD, 1);
}

// Round 6
// 627.723 us; speedup vs baseline: 7.7337x; 1.5008x over previous
//
#include <hip/hip_runtime.h>
#include <cstdint>
#include <cstddef>

typedef unsigned short ushort_t;
typedef short    bf16x8 __attribute__((ext_vector_type(8)));   // MFMA A/B frag (4 VGPR)
typedef float    f32x4  __attribute__((ext_vector_type(4)));   // MFMA C/D frag
typedef uint4    __attribute__((may_alias)) uint4_a;
typedef uint2    __attribute__((may_alias)) uint2_a;
typedef ushort4  __attribute__((may_alias)) ushort4_a;
typedef float4   __attribute__((may_alias)) float4_a;

constexpr int SEQ = 4096, HID = 2048, NHEADS = 16, NKVH = 4, HDIM = 128;
constexpr int QD  = NHEADS * HDIM;   // 2048
constexpr int KVD = NKVH * HDIM;     // 512

static __device__ __forceinline__ float bf2f(ushort_t u) {
    return __uint_as_float(((unsigned)u) << 16);
}
static __device__ __forceinline__ ushort_t f2bf(float f) {
    unsigned x = __float_as_uint(f);
    unsigned r = x + 0x7FFFu + ((x >> 16) & 1u);   // RNE
    return (ushort_t)(r >> 16);
}
static __device__ __forceinline__ unsigned pack2(float lo, float hi) {
    return (unsigned)f2bf(lo) | ((unsigned)f2bf(hi) << 16);
}

// ---------------------------------------------------------------------------
// X fp32 -> bf16 elementwise
// ---------------------------------------------------------------------------
__global__ __launch_bounds__(256) void cast_f32_bf16(
    const float* __restrict__ in, ushort_t* __restrict__ out, int n)
{
    int i = (blockIdx.x * 256 + threadIdx.x) * 8;
    if (i >= n) return;
    float4 a = *(const float4_a*)(in + i);
    float4 b = *(const float4_a*)(in + i + 4);
    uint4 o;
    o.x = pack2(a.x, a.y); o.y = pack2(a.z, a.w);
    o.z = pack2(b.x, b.y); o.w = pack2(b.z, b.w);
    *(uint4_a*)(out + i) = o;
}

// ---------------------------------------------------------------------------
// W[K,N] fp32 -> WT[N,K] bf16 (32x32 LDS-tiled transpose+cast)
// ---------------------------------------------------------------------------
__global__ __launch_bounds__(256) void transpose_cast(
    const float* __restrict__ W, ushort_t* __restrict__ WT, int K, int N)
{
    __shared__ float tl[32][36];
    const int k0 = blockIdx.x * 32, n0 = blockIdx.y * 32;
    const int t  = threadIdx.x;
    {
        int i = t >> 3, jb = (t & 7) * 4;
        *(float4_a*)&tl[i][jb] = *(const float4_a*)(W + (size_t)(k0 + i) * N + n0 + jb);
    }
    __syncthreads();
    {
        int n = t >> 3, kb = (t & 7) * 4;
        ushort4 o;
        o.x = f2bf(tl[kb + 0][n]); o.y = f2bf(tl[kb + 1][n]);
        o.z = f2bf(tl[kb + 2][n]); o.w = f2bf(tl[kb + 3][n]);
        *(ushort4_a*)(WT + (size_t)(n0 + n) * K + k0 + kb) = o;
    }
}

// ---------------------------------------------------------------------------
// MFMA GEMM (unchanged from R5): C[M,N] = A[M,K] * Bt[N,K]^T, bf16 in, fp32 acc.
// ---------------------------------------------------------------------------
__global__ __launch_bounds__(256) void gemm_mfma(
    const ushort_t* __restrict__ A, int lda,
    const ushort_t* __restrict__ Bt, int ldb,
    void* __restrict__ C, int M, int N, int K, int out_f32)
{
    __shared__ ushort_t as[128][40];
    __shared__ ushort_t bs[128][40];

    const int t    = threadIdx.x;
    const int mb   = blockIdx.y * 128, nb = blockIdx.x * 128;
    const int w    = t >> 6, lane = t & 63, quad = lane >> 4, l15 = lane & 15;
    const int wm   = (w >> 1) * 64, wn = (w & 1) * 64;
    const int srow = t >> 1, koff = (t & 1) * 16;

    f32x4 acc[4][4];
#pragma unroll
    for (int i = 0; i < 4; i++)
#pragma unroll
        for (int j = 0; j < 4; j++) acc[i][j] = (f32x4)0.f;

    const ushort_t* Ag = A  + (size_t)(mb + srow) * lda + koff;
    const ushort_t* Bg = Bt + (size_t)(nb + srow) * ldb + koff;

    for (int kb = 0; kb < K; kb += 32) {
        uint4 av0 = *(const uint4_a*)(Ag + kb);
        uint4 av1 = *(const uint4_a*)(Ag + kb + 8);
        uint4 bv0 = *(const uint4_a*)(Bg + kb);
        uint4 bv1 = *(const uint4_a*)(Bg + kb + 8);
        __syncthreads();
        *(uint4_a*)&as[srow][koff]     = av0;
        *(uint4_a*)&as[srow][koff + 8] = av1;
        *(uint4_a*)&bs[srow][koff]     = bv0;
        *(uint4_a*)&bs[srow][koff + 8] = bv1;
        __syncthreads();

        bf16x8 af[4], bf[4];
#pragma unroll
        for (int mt = 0; mt < 4; mt++)
            af[mt] = *(const bf16x8*)&as[wm + mt * 16 + l15][quad * 8];
#pragma unroll
        for (int nt = 0; nt < 4; nt++)
            bf[nt] = *(const bf16x8*)&bs[wn + nt * 16 + l15][quad * 8];
#pragma unroll
        for (int mt = 0; mt < 4; mt++)
#pragma unroll
            for (int nt = 0; nt < 4; nt++)
                acc[mt][nt] = __builtin_amdgcn_mfma_f32_16x16x32_bf16(
                    af[mt], bf[nt], acc[mt][nt], 0, 0, 0);
    }

#pragma unroll
    for (int mt = 0; mt < 4; mt++)
#pragma unroll
        for (int nt = 0; nt < 4; nt++)
#pragma unroll
            for (int r = 0; r < 4; r++) {
                int row = mb + wm + mt * 16 + quad * 4 + r;
                int col = nb + wn + nt * 16 + l15;
                float v = acc[mt][nt][r];
                if (out_f32) ((float*)C)[(size_t)row * N + col] = v;
                else         ((ushort_t*)C)[(size_t)row * N + col] = f2bf(v);
            }
}

// ---------------------------------------------------------------------------
// RoPE in-place on bf16 [SEQ, nh*128]; precise sincosf.
// ---------------------------------------------------------------------------
__global__ __launch_bounds__(256) void rope_bf16(
    ushort_t* __restrict__ buf, int nh, const int* __restrict__ pos_ids)
{
    int idx  = blockIdx.x * 256 + threadIdx.x;
    int i    = idx & 63;
    int rem  = idx >> 6;
    int head = rem % nh;
    int s    = rem / nh;
    if (s >= SEQ) return;

    float pos = (float)pos_ids[s];
    float ang = pos * __expf(-(float)i * 0.14391156831212787f);
    float c, sn;
    sincosf(ang, &sn, &c);

    ushort_t* p = buf + (size_t)s * (nh * HDIM) + head * HDIM;
    float x0 = bf2f(p[i]);
    float x1 = bf2f(p[i + 64]);
    p[i]      = f2bf(x0 * c - x1 * sn);
    p[i + 64] = f2bf(x1 * c + x0 * sn);
}

// ---------------------------------------------------------------------------
// Flash attention v2 (R6): block = 128 q-rows x one head, 64-key tiles,
// 4 waves (wave = 32 q-rows). S computed TRANSPOSED (K·Q^T) so softmax key-
// reduction is in-register + 2 shfl. K and V^T staged in LDS; P LDS round-trip
// (bf16, wave-private). Prefetch next K/V tile during compute.
// Per wave-iter: 64 MFMA. Q/O alias in-place (regs first, write last).
// ---------------------------------------------------------------------------
__global__ __launch_bounds__(256, 2) void flash_mfma(
    const ushort_t* Q, const ushort_t* __restrict__ Kb,
    const ushort_t* __restrict__ Vb, const int* __restrict__ amask,
    ushort_t* O)
{
    __shared__ ushort_t ks[64][136];     // K tile [key][dim], 272B rows
    __shared__ ushort_t vt[128][72];     // V^T tile [dim][key], 144B rows
    __shared__ ushort_t pm[4][32][72];   // per-wave P [q][key] bf16, 144B rows
    __shared__ float    bias[64];        // amask additive bias per key

    const int t = threadIdx.x, w = t >> 6, lane = t & 63;
    const int quad = lane >> 4, l15 = lane & 15;
    const int h = blockIdx.x, kvh = h >> 2;
    const int q0 = (gridDim.y - 1 - blockIdx.y) * 128;   // big tiles dispatch first
    const int q0w = q0 + w * 32;

    // Q B-frags (register resident): qf[nt][c] = Q[q0w+nt*16+l15][c*32+quad*8 ..+7]
    bf16x8 qf[2][4];
#pragma unroll
    for (int nt = 0; nt < 2; nt++) {
        const ushort_t* qp = Q + (size_t)(q0w + nt * 16 + l15) * QD + h * HDIM;
#pragma unroll
        for (int c = 0; c < 4; c++)
            qf[nt][c] = *(const bf16x8*)(qp + c * 32 + quad * 8);
    }

    f32x4 accO[2][8];
#pragma unroll
    for (int i = 0; i < 2; i++)
#pragma unroll
        for (int j = 0; j < 8; j++) accO[i][j] = (f32x4)0.f;
    float m_s[2] = {-1e30f, -1e30f}, l_s[2] = {0.f, 0.f};
    const float scale = 0.08838834764831845f;   // 1/sqrt(128)

    // staging maps
    const int kkey = t >> 2,  kdb = (t & 3) * 32;    // K: 4 x uint4 (64B contig)
    const int vkp  = t & 31,  vdb = (t >> 5) * 16;   // V: keys 2vkp,2vkp+1, dims vdb..+15

    uint4 kst[4], va[2], vb2[2];
    float bst = 0.f;
    auto stage_load = [&](int kt) {
        const int k0 = kt * 64;
        const ushort_t* kp = Kb + (size_t)(k0 + kkey) * KVD + kvh * HDIM + kdb;
#pragma unroll
        for (int l = 0; l < 4; l++) kst[l] = *(const uint4_a*)(kp + l * 8);
        const ushort_t* vp = Vb + (size_t)(k0 + 2 * vkp) * KVD + kvh * HDIM + vdb;
        va[0]  = *(const uint4_a*)vp;
        va[1]  = *(const uint4_a*)(vp + 8);
        vb2[0] = *(const uint4_a*)(vp + KVD);
        vb2[1] = *(const uint4_a*)(vp + KVD + 8);
        if (t < 64) bst = amask[k0 + t] ? 0.f : -1e30f;
    };

    const int nkt = (q0 >> 6) + 2;   // keys 0 .. q0+127
    stage_load(0);

    for (int kt = 0; kt < nkt; kt++) {
        const int k0 = kt * 64;
        __syncthreads();   // prev iter's LDS fully consumed
        // ---- write staged tile to LDS ----
#pragma unroll
        for (int l = 0; l < 4; l++)
            *(uint4_a*)&ks[kkey][kdb + l * 8] = kst[l];
        {
            unsigned aw[8] = {va[0].x, va[0].y, va[0].z, va[0].w,
                              va[1].x, va[1].y, va[1].z, va[1].w};
            unsigned bw[8] = {vb2[0].x, vb2[0].y, vb2[0].z, vb2[0].w,
                              vb2[1].x, vb2[1].y, vb2[1].z, vb2[1].w};
#pragma unroll
            for (int i = 0; i < 8; i++) {
                unsigned lo = (aw[i] & 0xFFFFu) | (bw[i] << 16);
                unsigned hi = (aw[i] >> 16) | (bw[i] & 0xFFFF0000u);
                *(unsigned*)&vt[vdb + 2 * i][2 * vkp]     = lo;
                *(unsigned*)&vt[vdb + 2 * i + 1][2 * vkp] = hi;
            }
        }
        if (t < 64) bias[t] = bst;
        __syncthreads();
        // ---- prefetch next tile while computing this one ----
        if (kt + 1 < nkt) stage_load(kt + 1);

        // ---- S^T = K Q^T : A=K[key][d], B=Q[q][d] -> D[key][q] ----
        f32x4 s[4][2];
#pragma unroll
        for (int mt = 0; mt < 4; mt++)
#pragma unroll
            for (int nt = 0; nt < 2; nt++) s[mt][nt] = (f32x4)0.f;
#pragma unroll
        for (int c = 0; c < 4; c++)
#pragma unroll
            for (int mt = 0; mt < 4; mt++) {
                bf16x8 kf = *(const bf16x8*)&ks[mt * 16 + l15][c * 32 + quad * 8];
#pragma unroll
                for (int nt = 0; nt < 2; nt++)
                    s[mt][nt] = __builtin_amdgcn_mfma_f32_16x16x32_bf16(
                        kf, qf[nt][c], s[mt][nt], 0, 0, 0);
            }

        // ---- masked online softmax along keys (register dim + 2 shfl) ----
        float bias_r[4][4];
#pragma unroll
        for (int mt = 0; mt < 4; mt++) {
            float4 b4 = *(const float4_a*)&bias[mt * 16 + quad * 4];
            bias_r[mt][0] = b4.x; bias_r[mt][1] = b4.y;
            bias_r[mt][2] = b4.z; bias_r[mt][3] = b4.w;
        }
        float alpha[2];
#pragma unroll
        for (int nt = 0; nt < 2; nt++) {
            const int qg = q0w + nt * 16 + l15;
            float vals[4][4];
            float mx = -1e30f;
#pragma unroll
            for (int mt = 0; mt < 4; mt++)
#pragma unroll
                for (int r = 0; r < 4; r++) {
                    int kg = k0 + mt * 16 + quad * 4 + r;
                    float v = fmaf(s[mt][nt][r], scale, bias_r[mt][r]);
                    v = (kg > qg) ? -1e30f : v;
                    vals[mt][r] = v;
                    mx = fmaxf(mx, v);
                }
            mx = fmaxf(mx, __shfl_xor(mx, 16));
            mx = fmaxf(mx, __shfl_xor(mx, 32));
            float mnew = fmaxf(m_s[nt], mx);
            alpha[nt] = __expf(m_s[nt] - mnew);
            m_s[nt] = mnew;
            float sum = 0.f;
#pragma unroll
            for (int mt = 0; mt < 4; mt++) {
                float p0 = __expf(vals[mt][0] - mnew);
                float p1 = __expf(vals[mt][1] - mnew);
                float p2 = __expf(vals[mt][2] - mnew);
                float p3 = __expf(vals[mt][3] - mnew);
                sum += (p0 + p1) + (p2 + p3);
                uint2 pw;
                pw.x = pack2(p0, p1);
                pw.y = pack2(p2, p3);
                *(uint2_a*)&pm[w][nt * 16 + l15][mt * 16 + quad * 4] = pw;
            }
            sum += __shfl_xor(sum, 16);
            sum += __shfl_xor(sum, 32);
            l_s[nt] = l_s[nt] * alpha[nt] + sum;
        }

        // ---- rescale accO by alpha (broadcast lane-q -> register-q) ----
#pragma unroll
        for (int mt2 = 0; mt2 < 2; mt2++) {
            float a0 = __shfl(alpha[mt2], quad * 4 + 0);
            float a1 = __shfl(alpha[mt2], quad * 4 + 1);
            float a2 = __shfl(alpha[mt2], quad * 4 + 2);
            float a3 = __shfl(alpha[mt2], quad * 4 + 3);
#pragma unroll
            for (int nt8 = 0; nt8 < 8; nt8++) {
                f32x4 a = accO[mt2][nt8];
                a[0] *= a0; a[1] *= a1; a[2] *= a2; a[3] *= a3;
                accO[mt2][nt8] = a;
            }
        }

        // ---- O += P V : A=P[q][key] (wave-private LDS), B=V^T[d][key] ----
#pragma unroll
        for (int kc = 0; kc < 2; kc++) {
            bf16x8 pf[2];
#pragma unroll
            for (int mt2 = 0; mt2 < 2; mt2++)
                pf[mt2] = *(const bf16x8*)&pm[w][mt2 * 16 + l15][kc * 32 + quad * 8];
#pragma unroll
            for (int nt8 = 0; nt8 < 8; nt8++) {
                bf16x8 vf = *(const bf16x8*)&vt[nt8 * 16 + l15][kc * 32 + quad * 8];
#pragma unroll
                for (int mt2 = 0; mt2 < 2; mt2++)
                    accO[mt2][nt8] = __builtin_amdgcn_mfma_f32_16x16x32_bf16(
                        pf[mt2], vf, accO[mt2][nt8], 0, 0, 0);
            }
        }
    }

    // ---- epilogue: normalize rows, store bf16 in-place ----
    float linv[2] = {1.0f / l_s[0], 1.0f / l_s[1]};
#pragma unroll
    for (int mt2 = 0; mt2 < 2; mt2++)
#pragma unroll
        for (int r = 0; r < 4; r++) {
            float lr = __shfl(linv[mt2], quad * 4 + r);
            int row = q0w + mt2 * 16 + quad * 4 + r;
            ushort_t* op = O + (size_t)row * QD + h * HDIM;
#pragma unroll
            for (int nt8 = 0; nt8 < 8; nt8++)
                op[nt8 * 16 + l15] = f2bf(accO[mt2][nt8][r] * lr);
        }
}

// ---------------------------------------------------------------------------
// Memory plan (unchanged): ws = qbuf 16MB | kbuf 4MB | vbuf 4MB (woT reuses
// kbuf after flash). d_out = wqT/wkT/wvT/xb scratch until the final GEMM.
// ---------------------------------------------------------------------------
extern "C" void kernel_launch(void* const* d_in, const int* in_sizes, int n_in,
                              void* d_out, int out_size, void* d_ws, size_t ws_size,
                              hipStream_t stream)
{
    const float* x     = (const float*)d_in[0];
    const int*   amask = (const int*)d_in[1];
    const int*   pos   = (const int*)d_in[2];
    const float* wq    = (const float*)d_in[3];
    const float* wk    = (const float*)d_in[4];
    const float* wv    = (const float*)d_in[5];
    const float* wo    = (const float*)d_in[6];
    float* out = (float*)d_out;

    ushort_t* wqT = (ushort_t*)d_out;
    ushort_t* wkT = wqT + (size_t)QD * HID;
    ushort_t* wvT = wkT + (size_t)KVD * HID;
    ushort_t* xb  = wvT + (size_t)KVD * HID;

    ushort_t* qbuf = (ushort_t*)d_ws;
    ushort_t* kbuf = qbuf + (size_t)SEQ * QD;
    ushort_t* vbuf = kbuf + (size_t)SEQ * KVD;
    ushort_t* woT  = kbuf;

    cast_f32_bf16<<<SEQ * HID / 8 / 256, 256, 0, stream>>>(x, xb, SEQ * HID);
    transpose_cast<<<dim3(HID / 32, QD / 32),  256, 0, stream>>>(wq, wqT, HID, QD);
    transpose_cast<<<dim3(HID / 32, KVD / 32), 256, 0, stream>>>(wk, wkT, HID, KVD);
    transpose_cast<<<dim3(HID / 32, KVD / 32), 256, 0, stream>>>(wv, wvT, HID, KVD);

    gemm_mfma<<<dim3(QD / 128,  SEQ / 128), 256, 0, stream>>>(xb, HID, wqT, HID, qbuf, SEQ, QD,  HID, 0);
    gemm_mfma<<<dim3(KVD / 128, SEQ / 128), 256, 0, stream>>>(xb, HID, wkT, HID, kbuf, SEQ, KVD, HID, 0);
    gemm_mfma<<<dim3(KVD / 128, SEQ / 128), 256, 0, stream>>>(xb, HID, wvT, HID, vbuf, SEQ, KVD, HID, 0);

    rope_bf16<<<SEQ * NHEADS * 64 / 256, 256, 0, stream>>>(qbuf, NHEADS, pos);
    rope_bf16<<<SEQ * NKVH  * 64 / 256, 256, 0, stream>>>(kbuf, NKVH, pos);

    flash_mfma<<<dim3(NHEADS, SEQ / 128), 256, 0, stream>>>(qbuf, kbuf, vbuf, amask, qbuf);

    transpose_cast<<<dim3(QD / 32, HID / 32), 256, 0, stream>>>(wo, woT, QD, HID);
    gemm_mfma<<<dim3(HID / 128, SEQ / 128), 256, 0, stream>>>(qbuf, QD, woT, QD, out, SEQ, HID, QD, 1);
}

// Round 7
// 522.541 us; speedup vs baseline: 9.2904x; 1.2013x over previous
//
#include <hip/hip_runtime.h>
#include <cstdint>
#include <cstddef>

typedef unsigned short ushort_t;
typedef short    bf16x8 __attribute__((ext_vector_type(8)));   // MFMA A/B frag (4 VGPR)
typedef float    f32x4  __attribute__((ext_vector_type(4)));   // MFMA C/D frag
typedef uint4    __attribute__((may_alias)) uint4_a;
typedef ushort4  __attribute__((may_alias)) ushort4_a;
typedef float4   __attribute__((may_alias)) float4_a;
typedef unsigned __attribute__((may_alias)) uint_a;

constexpr int SEQ = 4096, HID = 2048, NHEADS = 16, NKVH = 4, HDIM = 128;
constexpr int QD  = NHEADS * HDIM;   // 2048
constexpr int KVD = NKVH * HDIM;     // 512
constexpr int KVL = 2 * KVD;         // 1024: interleaved k|v row stride

static __device__ __forceinline__ float bf2f(ushort_t u) {
    return __uint_as_float(((unsigned)u) << 16);
}
static __device__ __forceinline__ ushort_t f2bf(float f) {
    unsigned x = __float_as_uint(f);
    unsigned r = x + 0x7FFFu + ((x >> 16) & 1u);   // RNE
    return (ushort_t)(r >> 16);
}
static __device__ __forceinline__ unsigned pack2(float lo, float hi) {
    return (unsigned)f2bf(lo) | ((unsigned)f2bf(hi) << 16);
}

// async global->LDS, 16B per lane; LDS dest = wave-uniform base + lane*16
static __device__ __forceinline__ void gld16(const ushort_t* g, ushort_t* l) {
    __builtin_amdgcn_global_load_lds(
        (const __attribute__((address_space(1))) unsigned*)g,
        (__attribute__((address_space(3))) unsigned*)l, 16, 0, 0);
}

// ---------------------------------------------------------------------------
// X fp32 -> bf16 elementwise
// ---------------------------------------------------------------------------
__global__ __launch_bounds__(256) void cast_f32_bf16(
    const float* __restrict__ in, ushort_t* __restrict__ out, int n)
{
    int i = (blockIdx.x * 256 + threadIdx.x) * 8;
    if (i >= n) return;
    float4 a = *(const float4_a*)(in + i);
    float4 b = *(const float4_a*)(in + i + 4);
    uint4 o;
    o.x = pack2(a.x, a.y); o.y = pack2(a.z, a.w);
    o.z = pack2(b.x, b.y); o.w = pack2(b.z, b.w);
    *(uint4_a*)(out + i) = o;
}

// ---------------------------------------------------------------------------
// W[K,N] fp32 -> WT[N,K] bf16 (32x32 LDS-tiled transpose+cast)
// ---------------------------------------------------------------------------
__global__ __launch_bounds__(256) void transpose_cast(
    const float* __restrict__ W, ushort_t* __restrict__ WT, int K, int N)
{
    __shared__ float tl[32][36];
    const int k0 = blockIdx.x * 32, n0 = blockIdx.y * 32;
    const int t  = threadIdx.x;
    {
        int i = t >> 3, jb = (t & 7) * 4;
        *(float4_a*)&tl[i][jb] = *(const float4_a*)(W + (size_t)(k0 + i) * N + n0 + jb);
    }
    __syncthreads();
    {
        int n = t >> 3, kb = (t & 7) * 4;
        ushort4 o;
        o.x = f2bf(tl[kb + 0][n]); o.y = f2bf(tl[kb + 1][n]);
        o.z = f2bf(tl[kb + 2][n]); o.w = f2bf(tl[kb + 3][n]);
        *(ushort4_a*)(WT + (size_t)(n0 + n) * K + k0 + kb) = o;
    }
}

// ---------------------------------------------------------------------------
// m97-style MFMA GEMM: C = A[M,K] * Bt[N,K]^T, bf16 in, fp32 acc.
// 256 thr / 4 waves, tile 128x128, BK=32, global_load_lds(16B) into unpadded
// XOR-swizzled LDS (stored chunk = chunk ^ (row&3); chunk = 8 shorts).
// Epilogue routes cols < split -> C1 (ld1), else C2 (ld2). out_f32 -> C1 fp32.
// ---------------------------------------------------------------------------
__global__ __launch_bounds__(256) void gemm_mfma(
    const ushort_t* __restrict__ A, int lda,
    const ushort_t* __restrict__ Bt, int ldb,
    void* __restrict__ C1, int ld1, void* __restrict__ C2, int ld2,
    int split, int N, int K, int out_f32)
{
    __shared__ ushort_t as[128 * 32];   // 8 KB, unpadded (dma-contiguous)
    __shared__ ushort_t bs[128 * 32];

    const int t    = threadIdx.x;
    const int mb   = blockIdx.y * 128, nb = blockIdx.x * 128;
    const int w    = t >> 6, lane = t & 63, quad = lane >> 4, l15 = lane & 15;
    const int wm   = (w >> 1) * 64, wn = (w & 1) * 64;

    // dma maps: round r in {0,1}: rows (r*4+w)*16 + lane/4, chunk lane&3,
    // global chunk = (lane&3) ^ (row&3)
    const int dr_row = lane >> 2, dr_c = lane & 3;
    const int rA0 = w * 16 + dr_row, rA1 = 64 + w * 16 + dr_row;
    const ushort_t* a0p = A  + (size_t)(mb + rA0) * lda + (dr_c ^ (rA0 & 3)) * 8;
    const ushort_t* a1p = A  + (size_t)(mb + rA1) * lda + (dr_c ^ (rA1 & 3)) * 8;
    const ushort_t* b0p = Bt + (size_t)(nb + rA0) * ldb + (dr_c ^ (rA0 & 3)) * 8;
    const ushort_t* b1p = Bt + (size_t)(nb + rA1) * ldb + (dr_c ^ (rA1 & 3)) * 8;
    ushort_t* asb0 = &as[(w) * 512];        ushort_t* asb1 = &as[(4 + w) * 512];
    ushort_t* bsb0 = &bs[(w) * 512];        ushort_t* bsb1 = &bs[(4 + w) * 512];

    f32x4 acc[4][4];
#pragma unroll
    for (int i = 0; i < 4; i++)
#pragma unroll
        for (int j = 0; j < 4; j++) acc[i][j] = (f32x4)0.f;

    const int chunk = quad ^ (l15 & 3);   // swizzled frag chunk

    for (int kb = 0; kb < K; kb += 32) {
        __syncthreads();                   // prev iter's frag reads done
        gld16(a0p + kb, asb0);
        gld16(a1p + kb, asb1);
        gld16(b0p + kb, bsb0);
        gld16(b1p + kb, bsb1);
        __syncthreads();                   // compiler drains vmcnt before barrier

        bf16x8 af[4], bf[4];
#pragma unroll
        for (int mt = 0; mt < 4; mt++)
            af[mt] = *(const bf16x8*)&as[(wm + mt * 16 + l15) * 32 + chunk * 8];
#pragma unroll
        for (int nt = 0; nt < 4; nt++)
            bf[nt] = *(const bf16x8*)&bs[(wn + nt * 16 + l15) * 32 + chunk * 8];
#pragma unroll
        for (int mt = 0; mt < 4; mt++)
#pragma unroll
            for (int nt = 0; nt < 4; nt++)
                acc[mt][nt] = __builtin_amdgcn_mfma_f32_16x16x32_bf16(
                    af[mt], bf[nt], acc[mt][nt], 0, 0, 0);
    }

#pragma unroll
    for (int mt = 0; mt < 4; mt++)
#pragma unroll
        for (int nt = 0; nt < 4; nt++) {
            int colg = nb + wn + nt * 16 + l15;
#pragma unroll
            for (int r = 0; r < 4; r++) {
                int row = mb + wm + mt * 16 + quad * 4 + r;
                float v = acc[mt][nt][r];
                if (out_f32)            ((float*)C1)[(size_t)row * ld1 + colg] = v;
                else if (colg < split)  ((ushort_t*)C1)[(size_t)row * ld1 + colg] = f2bf(v);
                else                    ((ushort_t*)C2)[(size_t)row * ld2 + colg - split] = f2bf(v);
            }
        }
}

// ---------------------------------------------------------------------------
// RoPE in-place on bf16 [SEQ, ld] buffer, nh heads; precise sincosf.
// ---------------------------------------------------------------------------
__global__ __launch_bounds__(256) void rope_bf16(
    ushort_t* __restrict__ buf, int ld, int nh, const int* __restrict__ pos_ids)
{
    int idx  = blockIdx.x * 256 + threadIdx.x;
    int i    = idx & 63;
    int rem  = idx >> 6;
    int head = rem % nh;
    int s    = rem / nh;
    if (s >= SEQ) return;

    float pos = (float)pos_ids[s];
    float ang = pos * __expf(-(float)i * 0.14391156831212787f);
    float c, sn;
    sincosf(ang, &sn, &c);

    ushort_t* p = buf + (size_t)s * ld + head * HDIM;
    float x0 = bf2f(p[i]);
    float x1 = bf2f(p[i + 64]);
    p[i]      = f2bf(x0 * c - x1 * sn);
    p[i + 64] = f2bf(x1 * c + x0 * sn);
}

// ---------------------------------------------------------------------------
// Flash attention v3 (R7): 512 threads = 8 waves x 16 q-rows (128 q / block),
// 64-key tiles. S^T = K·Q^T (softmax keys in registers + 2 shfl). K/V register-
// prefetched into LDS (ks padded, vt transposed). P transposed C->A layout
// IN-REGISTER via ds_bpermute (no P LDS, 36KB total -> high occupancy).
// exp2-domain softmax. Q/O alias in-place. kv interleaved buffer (stride KVL).
// ---------------------------------------------------------------------------
__global__ __launch_bounds__(512, 4) void flash_mfma(
    const ushort_t* Q, const ushort_t* __restrict__ KV,
    const int* __restrict__ amask, ushort_t* O)
{
    __shared__ ushort_t ks[64][136];     // K tile [key][dim], 272B rows
    __shared__ ushort_t vt[128][72];     // V^T tile [dim][key], 144B rows
    __shared__ float    bias[64];

    const int t = threadIdx.x, w = t >> 6, lane = t & 63;
    const int quad = lane >> 4, l15 = lane & 15;
    const int h = blockIdx.x, kvh = h >> 2;
    const int q0 = (gridDim.y - 1 - blockIdx.y) * 128;
    const int q0w = q0 + w * 16;
    const int kcol = kvh * HDIM, vcol = KVD + kvh * HDIM;

    // Q B-frags: qf[c] = Q[q0w + l15][c*32 + quad*8 ..+8]
    bf16x8 qf[4];
    {
        const ushort_t* qp = Q + (size_t)(q0w + l15) * QD + h * HDIM;
#pragma unroll
        for (int c = 0; c < 4; c++)
            qf[c] = *(const bf16x8*)(qp + c * 32 + quad * 8);
    }

    f32x4 accO[8];
#pragma unroll
    for (int j = 0; j < 8; j++) accO[j] = (f32x4)0.f;
    float m_s = -1e30f, l_s = 0.f;
    const float scale2 = 0.08838834764831845f * 1.44269504088896340f; // /sqrt(128)*log2e

    // staging maps
    const int krow = t >> 3,  kdo = (t & 7) * 16;    // K: 1 key row, 16 dims
    const int vkp  = t & 31,  vdg = t >> 5;          // V: keys 2vkp,2vkp+1, dims vdg*8..+8

    // bpermute indices for P transpose: quad' = 2*(quad&1) + (t4>>1)
    int bpi[4];
#pragma unroll
    for (int t4 = 0; t4 < 4; t4++)
        bpi[t4] = ((2 * (quad & 1) + (t4 >> 1)) * 16 + l15) * 4;
    const bool hi_half = (quad >> 1) != 0;           // selects mt' = 2kc+1

    uint4 kst[2], va, vb;
    float bst = 0.f;
    auto stage_load = [&](int kt) {
        const int k0 = kt * 64;
        const ushort_t* kp = KV + (size_t)(k0 + krow) * KVL + kcol + kdo;
        kst[0] = *(const uint4_a*)kp;
        kst[1] = *(const uint4_a*)(kp + 8);
        const ushort_t* vp = KV + (size_t)(k0 + 2 * vkp) * KVL + vcol + vdg * 8;
        va = *(const uint4_a*)vp;
        vb = *(const uint4_a*)(vp + KVL);
        if (t < 64) bst = amask[k0 + t] ? 0.f : -1e30f;
    };

    const int nkt = (q0 >> 6) + 2;   // keys 0 .. q0+127
    stage_load(0);

    for (int kt = 0; kt < nkt; kt++) {
        const int k0 = kt * 64;
        __syncthreads();   // prev tile fully consumed
        *(uint4_a*)&ks[krow][kdo]     = kst[0];
        *(uint4_a*)&ks[krow][kdo + 8] = kst[1];
        {
            unsigned aw[4] = {va.x, va.y, va.z, va.w};
            unsigned bw[4] = {vb.x, vb.y, vb.z, vb.w};
#pragma unroll
            for (int i = 0; i < 4; i++) {
                *(uint_a*)&vt[vdg * 8 + 2 * i][2 * vkp] =
                    (aw[i] & 0xFFFFu) | (bw[i] << 16);
                *(uint_a*)&vt[vdg * 8 + 2 * i + 1][2 * vkp] =
                    (aw[i] >> 16) | (bw[i] & 0xFFFF0000u);
            }
        }
        if (t < 64) bias[t] = bst;
        __syncthreads();
        if (kt + 1 < nkt) stage_load(kt + 1);   // full compute window to land

        if (k0 > q0w + 15) continue;   // tile fully masked for this wave

        // ---- S^T = K Q^T ----
        f32x4 s[4];
#pragma unroll
        for (int mt = 0; mt < 4; mt++) s[mt] = (f32x4)0.f;
#pragma unroll
        for (int c = 0; c < 4; c++)
#pragma unroll
            for (int mt = 0; mt < 4; mt++) {
                bf16x8 kf = *(const bf16x8*)&ks[mt * 16 + l15][c * 32 + quad * 8];
                s[mt] = __builtin_amdgcn_mfma_f32_16x16x32_bf16(kf, qf[c], s[mt], 0, 0, 0);
            }

        // ---- masked online softmax (exp2 domain); q-row = l15, keys in regs ----
        const int qg = q0w + l15;
        const bool full = (k0 + 63 <= q0w);    // no causal masking needed
        float p[4][4];
        float mx = -1e30f;
#pragma unroll
        for (int mt = 0; mt < 4; mt++) {
            float4 b4 = *(const float4_a*)&bias[mt * 16 + quad * 4];
            float br[4] = {b4.x, b4.y, b4.z, b4.w};
#pragma unroll
            for (int r = 0; r < 4; r++) {
                float v = fmaf(s[mt][r], scale2, br[r]);
                if (!full) {
                    int kg = k0 + mt * 16 + quad * 4 + r;
                    v = (kg > qg) ? -1e30f : v;
                }
                p[mt][r] = v;
                mx = fmaxf(mx, v);
            }
        }
        mx = fmaxf(mx, __shfl_xor(mx, 16));
        mx = fmaxf(mx, __shfl_xor(mx, 32));
        float mnew = fmaxf(m_s, mx);
        float alpha = exp2f(m_s - mnew);
        m_s = mnew;
        float sum = 0.f;
        unsigned wlo[4], whi[4];
#pragma unroll
        for (int mt = 0; mt < 4; mt++) {
            float p0 = exp2f(p[mt][0] - mnew);
            float p1 = exp2f(p[mt][1] - mnew);
            float p2 = exp2f(p[mt][2] - mnew);
            float p3 = exp2f(p[mt][3] - mnew);
            sum += (p0 + p1) + (p2 + p3);
            wlo[mt] = pack2(p0, p1);
            whi[mt] = pack2(p2, p3);
        }
        sum += __shfl_xor(sum, 16);
        sum += __shfl_xor(sum, 32);
        l_s = l_s * alpha + sum;

        // ---- rescale accO (broadcast alpha lane-q -> register-q) ----
        {
            float a0 = __shfl(alpha, quad * 4 + 0);
            float a1 = __shfl(alpha, quad * 4 + 1);
            float a2 = __shfl(alpha, quad * 4 + 2);
            float a3 = __shfl(alpha, quad * 4 + 3);
#pragma unroll
            for (int j = 0; j < 8; j++) {
                f32x4 a = accO[j];
                a[0] *= a0; a[1] *= a1; a[2] *= a2; a[3] *= a3;
                accO[j] = a;
            }
        }

        // ---- P transpose C->A layout via ds_bpermute; then O += P V ----
#pragma unroll
        for (int kc = 0; kc < 2; kc++) {
            union { unsigned u[4]; bf16x8 v; } pf;
#pragma unroll
            for (int t4 = 0; t4 < 4; t4++) {
                unsigned slo = (t4 & 1) ? whi[2 * kc]     : wlo[2 * kc];
                unsigned shi = (t4 & 1) ? whi[2 * kc + 1] : wlo[2 * kc + 1];
                int ra = __builtin_amdgcn_ds_bpermute(bpi[t4], (int)slo);
                int rb = __builtin_amdgcn_ds_bpermute(bpi[t4], (int)shi);
                pf.u[t4] = (unsigned)(hi_half ? rb : ra);
            }
#pragma unroll
            for (int n8 = 0; n8 < 8; n8++) {
                bf16x8 vf = *(const bf16x8*)&vt[n8 * 16 + l15][kc * 32 + quad * 8];
                accO[n8] = __builtin_amdgcn_mfma_f32_16x16x32_bf16(pf.v, vf, accO[n8], 0, 0, 0);
            }
        }
    }

    // ---- epilogue: normalize rows, store bf16 in-place over Q region ----
    float linv = 1.0f / l_s;
#pragma unroll
    for (int r = 0; r < 4; r++) {
        float lr = __shfl(linv, quad * 4 + r);
        int row = q0w + quad * 4 + r;
        ushort_t* op = O + (size_t)row * QD + h * HDIM;
#pragma unroll
        for (int n8 = 0; n8 < 8; n8++)
            op[n8 * 16 + l15] = f2bf(accO[n8][r] * lr);
    }
}

// ---------------------------------------------------------------------------
// Memory plan: ws = qbuf/att 16MB | kvbuf (k|v interleaved) 8MB | (woT 8MB
// overwrites kvbuf after flash). d_out scratch until O-GEMM: wqkvT 12MB | xb 16MB.
// ---------------------------------------------------------------------------
extern "C" void kernel_launch(void* const* d_in, const int* in_sizes, int n_in,
                              void* d_out, int out_size, void* d_ws, size_t ws_size,
                              hipStream_t stream)
{
    const float* x     = (const float*)d_in[0];
    const int*   amask = (const int*)d_in[1];
    const int*   pos   = (const int*)d_in[2];
    const float* wq    = (const float*)d_in[3];
    const float* wk    = (const float*)d_in[4];
    const float* wv    = (const float*)d_in[5];
    const float* wo    = (const float*)d_in[6];
    float* out = (float*)d_out;

    ushort_t* wqkvT = (ushort_t*)d_out;                    // [3072][2048] bf16
    ushort_t* xb    = wqkvT + (size_t)3072 * HID;          // [4096][2048] bf16

    ushort_t* qbuf  = (ushort_t*)d_ws;                     // [4096][2048]
    ushort_t* kvbuf = qbuf + (size_t)SEQ * QD;             // [4096][1024] k|v
    ushort_t* woT   = kvbuf;                               // [2048][2048] after flash

    cast_f32_bf16<<<SEQ * HID / 8 / 256, 256, 0, stream>>>(x, xb, SEQ * HID);
    transpose_cast<<<dim3(HID / 32, QD / 32),  256, 0, stream>>>(wq, wqkvT, HID, QD);
    transpose_cast<<<dim3(HID / 32, KVD / 32), 256, 0, stream>>>(wk, wqkvT + (size_t)QD * HID, HID, KVD);
    transpose_cast<<<dim3(HID / 32, KVD / 32), 256, 0, stream>>>(wv, wqkvT + (size_t)(QD + KVD) * HID, HID, KVD);

    // fused QKV projection: cols [0,2048) -> qbuf, [2048,3072) -> kvbuf
    gemm_mfma<<<dim3(3072 / 128, SEQ / 128), 256, 0, stream>>>(
        xb, HID, wqkvT, HID, qbuf, QD, kvbuf, KVL, QD, 3072, HID, 0);

    rope_bf16<<<SEQ * NHEADS * 64 / 256, 256, 0, stream>>>(qbuf, QD, NHEADS, pos);
    rope_bf16<<<SEQ * NKVH  * 64 / 256, 256, 0, stream>>>(kvbuf, KVL, NKVH, pos);

    flash_mfma<<<dim3(NHEADS, SEQ / 128), 512, 0, stream>>>(qbuf, kvbuf, amask, qbuf);

    transpose_cast<<<dim3(QD / 32, HID / 32), 256, 0, stream>>>(wo, woT, QD, HID);
    gemm_mfma<<<dim3(HID / 128, SEQ / 128), 256, 0, stream>>>(
        qbuf, QD, woT, QD, out, HID, out, HID, HID, HID, QD, 1);
}